// Round 3
// baseline (1034.942 us; speedup 1.0000x reference)
//
#include <hip/hip_runtime.h>
#include <cstdint>
#include <cstddef>

// ---------------------------------------------------------------------------
// QSAR D-MPNN, bf16 MFMA pipeline (round 3).
// Round-3 changes vs round-2 (absmax 37.0 vs thr 32.64 -> precision work):
//  * amsg kept in fp32 (k_amsg32) -> removes the largest per-depth bf16
//    rounding (|amsg| ~ 4x msg since relu outputs are positive).
//  * q kept in fp32 (GEMM fp32-out path) -> softmax logits lose one rounding.
//  * conv_fa moved after depth loop so amsg32 time-shares the cath/cur16
//    region: total ws 205.8 MB < 231 MB proven in round 2.
// ---------------------------------------------------------------------------

typedef float  floatx4  __attribute__((ext_vector_type(4)));
typedef short  bf16x8   __attribute__((ext_vector_type(8)));
typedef unsigned short ushort_t;
typedef unsigned short ushortx8 __attribute__((ext_vector_type(8)));

#define DEV __device__ __forceinline__

DEV float bf2f(ushort_t u) {
  union { unsigned int i; float f; } v; v.i = ((unsigned int)u) << 16; return v.f;
}
DEV ushort_t f2bf(float f) {
  union { float f; unsigned int i; } v; v.f = f;
  unsigned int r = v.i + 0x7FFFu + ((v.i >> 16) & 1u);   // RNE
  return (ushort_t)(r >> 16);
}

#define GLD16(gp, lp)                                                          \
  __builtin_amdgcn_global_load_lds(                                            \
      (const __attribute__((address_space(1))) void*)(gp),                     \
      (__attribute__((address_space(3))) void*)(lp), 16, 0, 0)

// ---------------------------------------------------------------------------
// f_bonds fp32 [131073][150] -> fb16 [131073][160] (k-pad zeros)
__global__ void k_conv_fb(const float* __restrict__ fb, ushort_t* __restrict__ dst) {
  int cid = blockIdx.x * 256 + threadIdx.x;
  if (cid >= 131073 * 20) return;
  int row = cid / 20, j = cid % 20;
  const float* s = fb + (size_t)row * 150;
  ushortx8 o;
#pragma unroll
  for (int e = 0; e < 8; e++) { int col = j * 8 + e; o[e] = (col < 150) ? f2bf(s[col]) : (ushort_t)0; }
  *(ushortx8*)(dst + (size_t)row * 160 + j * 8) = o;
}

// f_atoms fp32 [32769][139] -> cath [32769][544] cols 0..143 + 528..543
// (zero-padded); cols 144..527 already filled by final k_amsg. Rows 1..32768.
__global__ void k_conv_fa(const float* __restrict__ fa, ushort_t* __restrict__ cath) {
  int cid = blockIdx.x * 256 + threadIdx.x;
  if (cid >= 32768 * 20) return;
  int a = cid / 20 + 1, j = cid % 20;
  int chunk = (j < 18) ? j : (48 + j);          // 18->66 (cols 528..535), 19->67
  const float* s = fa + (size_t)a * 139;
  ushortx8 o;
#pragma unroll
  for (int e = 0; e < 8; e++) { int col = chunk * 8 + e; o[e] = (col < 139) ? f2bf(s[col]) : (ushort_t)0; }
  *(ushortx8*)(cath + (size_t)a * 544 + chunk * 8) = o;
}

// Weights -> bf16 transposed [N][Kpad].
__global__ void k_conv_wt(const float* __restrict__ Wi, const float* __restrict__ Wh,
                          const float* __restrict__ Wa, const float* __restrict__ Wb,
                          const float* __restrict__ Wo,
                          ushort_t* __restrict__ wti, ushort_t* __restrict__ wthx,
                          ushort_t* __restrict__ wta, ushort_t* __restrict__ wtb,
                          ushort_t* __restrict__ wto) {
  int cid = blockIdx.x * 256 + threadIdx.x;
  if (cid < 7680) {                       // wti [384][160]
    int n = cid / 20, kc = cid % 20; ushortx8 o;
#pragma unroll
    for (int e = 0; e < 8; e++) { int k = kc * 8 + e; o[e] = (k < 150) ? f2bf(Wi[(size_t)k * 384 + n]) : (ushort_t)0; }
    *(ushortx8*)(wti + (size_t)n * 160 + kc * 8) = o; return;
  }
  cid -= 7680;
  if (cid < 78336) {                      // wthx [3][384][544]: [W_h^T | W_i^T pad]
    int np = cid / 68, kc = cid % 68;
    int d = np / 384, n = np % 384; ushortx8 o;
#pragma unroll
    for (int e = 0; e < 8; e++) {
      float v;
      if (kc < 48) { int k = kc * 8 + e; v = Wh[(size_t)d * 147456 + (size_t)k * 384 + n]; }
      else { int k2 = (kc - 48) * 8 + e; v = (k2 < 150) ? Wi[(size_t)k2 * 384 + n] : 0.f; }
      o[e] = f2bf(v);
    }
    *(ushortx8*)(wthx + (size_t)np * 544 + kc * 8) = o; return;
  }
  cid -= 78336;
  if (cid < 18432) {                      // wta [384][384]
    int n = cid / 48, kc = cid % 48; ushortx8 o;
#pragma unroll
    for (int e = 0; e < 8; e++) { int k = kc * 8 + e; o[e] = f2bf(Wa[(size_t)k * 384 + n]); }
    *(ushortx8*)(wta + (size_t)n * 384 + kc * 8) = o; return;
  }
  cid -= 18432;
  if (cid < 18432) {                      // wtb
    int n = cid / 48, kc = cid % 48; ushortx8 o;
#pragma unroll
    for (int e = 0; e < 8; e++) { int k = kc * 8 + e; o[e] = f2bf(Wb[(size_t)k * 384 + n]); }
    *(ushortx8*)(wtb + (size_t)n * 384 + kc * 8) = o; return;
  }
  cid -= 18432;
  if (cid < 26112) {                      // wto [384][544] (cath col layout)
    int n = cid / 68, kc = cid % 68; ushortx8 o;
#pragma unroll
    for (int e = 0; e < 8; e++) {
      int k = kc * 8 + e; float v = 0.f;
      if (k < 139) v = Wo[(size_t)k * 384 + n];
      else if (k >= 144 && k < 528) v = Wo[(size_t)(k - 5) * 384 + n];
      o[e] = f2bf(v);
    }
    *(ushortx8*)(wto + (size_t)n * 544 + kc * 8) = o; return;
  }
}

// ---------------------------------------------------------------------------
// Stripe GEMM: one block owns 128 output rows x full N=384.
// 512 threads = 8 waves in 2(m) x 4(n); per wave 64 x 96 = 4x6 16x16 tiles.
// A split: cols [0,K1) from A1 (lda1), cols [K1,K1+K2) from A2 (lda2).
// out = [relu]( A @ Bt^T + bias ) -> Cf (fp32) if non-null else Cb (bf16).
__global__ __launch_bounds__(512) void k_gemm(
    const ushort_t* __restrict__ A1, int lda1, int K1,
    const ushort_t* __restrict__ A2, int lda2, int K2,
    const ushort_t* __restrict__ Bt, int ldb,
    ushort_t* __restrict__ Cb, float* __restrict__ Cf,
    const float* __restrict__ bias, int relu)
{
  __shared__ ushort_t LS[512 * 32] __attribute__((aligned(16)));  // 32 KiB
  const int tid = threadIdx.x;
  const int w = tid >> 6, l = tid & 63;
  const int m0 = blockIdx.x << 7;
  const int wm = w & 1, wn = w >> 1;
  const int lr = l & 15, quad = l >> 4;
  const int K = K1 + K2;

  floatx4 acc[4][6] = {};

  const int srow0 = (w << 6) + (l >> 2);
  const int scol = (l & 3) << 3;

  for (int k0 = 0; k0 < K; k0 += 32) {
#pragma unroll
    for (int g = 0; g < 4; g++) {
      const int cr = srow0 + g * 16;                      // 16-row groups
      ushort_t* lp = LS + (size_t)((w << 6) + (g << 4)) * 32;   // wave-uniform base
      if (cr < 128) {
        if (k0 < K1) GLD16(A1 + (size_t)(m0 + cr) * lda1 + k0 + scol, lp);
        else         GLD16(A2 + (size_t)(m0 + cr) * lda2 + (k0 - K1) + scol, lp);
      } else {
        GLD16(Bt + (size_t)(cr - 128) * ldb + k0 + scol, lp);
      }
    }
    __syncthreads();
    bf16x8 af[4], bfr[6];
#pragma unroll
    for (int mt = 0; mt < 4; mt++)
      af[mt] = *(const bf16x8*)(LS + (((wm << 6) + (mt << 4) + lr) << 5) + (quad << 3));
#pragma unroll
    for (int nt = 0; nt < 6; nt++)
      bfr[nt] = *(const bf16x8*)(LS + ((size_t)(128 + wn * 96 + (nt << 4) + lr) << 5) + (quad << 3));
#pragma unroll
    for (int mt = 0; mt < 4; mt++)
#pragma unroll
      for (int nt = 0; nt < 6; nt++)
        acc[mt][nt] = __builtin_amdgcn_mfma_f32_16x16x32_bf16(af[mt], bfr[nt], acc[mt][nt], 0, 0, 0);
    __syncthreads();
  }

#pragma unroll
  for (int mt = 0; mt < 4; mt++) {
#pragma unroll
    for (int nt = 0; nt < 6; nt++) {
      int colg = wn * 96 + (nt << 4) + lr;
      float bv = bias ? bias[colg] : 0.f;
#pragma unroll
      for (int r = 0; r < 4; r++) {
        int rowg = m0 + (wm << 6) + (mt << 4) + (quad << 2) + r;
        size_t off = (size_t)rowg * 384 + colg;
        float v = acc[mt][nt][r] + bv;
        if (relu) v = fmaxf(v, 0.f);
        if (Cf) Cf[off] = v;
        else    Cb[off] = f2bf(v);
      }
    }
  }
}

// ---------------------------------------------------------------------------
// amsg32[a] = sum_{k<4} msg[a2b[a][k]]  in fp32 (atoms 1..32768)
__global__ void k_amsg32(const ushort_t* __restrict__ msg, const int* __restrict__ a2b,
                         float* __restrict__ amsg) {
  int cid = blockIdx.x * 256 + threadIdx.x;
  if (cid >= 32768 * 48) return;
  int a = (cid / 48) + 1, c = cid % 48;
  const int4 nb = *(const int4*)(a2b + (size_t)a * 4);
  ushortx8 x0 = *(const ushortx8*)(msg + (size_t)nb.x * 384 + c * 8);
  ushortx8 x1 = *(const ushortx8*)(msg + (size_t)nb.y * 384 + c * 8);
  ushortx8 x2 = *(const ushortx8*)(msg + (size_t)nb.z * 384 + c * 8);
  ushortx8 x3 = *(const ushortx8*)(msg + (size_t)nb.w * 384 + c * 8);
  float4 lo, hi;
  lo.x = bf2f(x0[0]) + bf2f(x1[0]) + bf2f(x2[0]) + bf2f(x3[0]);
  lo.y = bf2f(x0[1]) + bf2f(x1[1]) + bf2f(x2[1]) + bf2f(x3[1]);
  lo.z = bf2f(x0[2]) + bf2f(x1[2]) + bf2f(x2[2]) + bf2f(x3[2]);
  lo.w = bf2f(x0[3]) + bf2f(x1[3]) + bf2f(x2[3]) + bf2f(x3[3]);
  hi.x = bf2f(x0[4]) + bf2f(x1[4]) + bf2f(x2[4]) + bf2f(x3[4]);
  hi.y = bf2f(x0[5]) + bf2f(x1[5]) + bf2f(x2[5]) + bf2f(x3[5]);
  hi.z = bf2f(x0[6]) + bf2f(x1[6]) + bf2f(x2[6]) + bf2f(x3[6]);
  hi.w = bf2f(x0[7]) + bf2f(x1[7]) + bf2f(x2[7]) + bf2f(x3[7]);
  float4* d = (float4*)(amsg + (size_t)a * 384 + c * 8);
  d[0] = lo; d[1] = hi;
}

// a_msg (bf16) for the readout concat: dst[a*544 + 144 + ...]
__global__ void k_amsg_cat(const ushort_t* __restrict__ msg, const int* __restrict__ a2b,
                           ushort_t* __restrict__ cath) {
  int cid = blockIdx.x * 256 + threadIdx.x;
  if (cid >= 32768 * 48) return;
  int a = (cid / 48) + 1, c = cid % 48;
  const int4 nb = *(const int4*)(a2b + (size_t)a * 4);
  ushortx8 x0 = *(const ushortx8*)(msg + (size_t)nb.x * 384 + c * 8);
  ushortx8 x1 = *(const ushortx8*)(msg + (size_t)nb.y * 384 + c * 8);
  ushortx8 x2 = *(const ushortx8*)(msg + (size_t)nb.z * 384 + c * 8);
  ushortx8 x3 = *(const ushortx8*)(msg + (size_t)nb.w * 384 + c * 8);
  ushortx8 o;
#pragma unroll
  for (int e = 0; e < 8; e++)
    o[e] = f2bf(bf2f(x0[e]) + bf2f(x1[e]) + bf2f(x2[e]) + bf2f(x3[e]));
  *(ushortx8*)(cath + (size_t)a * 544 + 144 + c * 8) = o;
}

// In-place build_t over rev-bond pairs (b0=2p+1, b1=b2revb[b0]):
//   t[b] = amsg32[b2a[b]] - msg[rev(b)], rounded once to bf16.
__global__ void k_buildt(const float* __restrict__ amsg, ushort_t* __restrict__ msg,
                         const int* __restrict__ b2a, const int* __restrict__ b2revb) {
  int cid = blockIdx.x * 256 + threadIdx.x;
  if (cid >= 65536 * 48) return;
  int p = cid / 48, c = cid % 48;
  int b0 = 2 * p + 1;
  int b1 = b2revb[b0];
  int a0 = b2a[b0], a1 = b2a[b1];
  ushortx8 m0v = *(const ushortx8*)(msg + (size_t)b0 * 384 + c * 8);
  ushortx8 m1v = *(const ushortx8*)(msg + (size_t)b1 * 384 + c * 8);
  const float4* s0p = (const float4*)(amsg + (size_t)a0 * 384 + c * 8);
  const float4* s1p = (const float4*)(amsg + (size_t)a1 * 384 + c * 8);
  float4 s0a = s0p[0], s0b = s0p[1];
  float4 s1a = s1p[0], s1b = s1p[1];
  ushortx8 o0, o1;
  o0[0] = f2bf(s0a.x - bf2f(m1v[0])); o0[1] = f2bf(s0a.y - bf2f(m1v[1]));
  o0[2] = f2bf(s0a.z - bf2f(m1v[2])); o0[3] = f2bf(s0a.w - bf2f(m1v[3]));
  o0[4] = f2bf(s0b.x - bf2f(m1v[4])); o0[5] = f2bf(s0b.y - bf2f(m1v[5]));
  o0[6] = f2bf(s0b.z - bf2f(m1v[6])); o0[7] = f2bf(s0b.w - bf2f(m1v[7]));
  o1[0] = f2bf(s1a.x - bf2f(m0v[0])); o1[1] = f2bf(s1a.y - bf2f(m0v[1]));
  o1[2] = f2bf(s1a.z - bf2f(m0v[2])); o1[3] = f2bf(s1a.w - bf2f(m0v[3]));
  o1[4] = f2bf(s1b.x - bf2f(m0v[4])); o1[5] = f2bf(s1b.y - bf2f(m0v[5]));
  o1[6] = f2bf(s1b.z - bf2f(m0v[6])); o1[7] = f2bf(s1b.w - bf2f(m0v[7]));
  *(ushortx8*)(msg + (size_t)b0 * 384 + c * 8) = o0;
  *(ushortx8*)(msg + (size_t)b1 * 384 + c * 8) = o1;
}

// ---------------------------------------------------------------------------
// Per-molecule attention: scores = q32@cur^T (fp32 q), row softmax fp32,
// z = att@cur -> bf16.
__global__ __launch_bounds__(256) void k_attn(const float* __restrict__ q32,
                                              const ushort_t* __restrict__ cur16,
                                              ushort_t* __restrict__ z16) {
  __shared__ ushort_t cs[32 * 392] __attribute__((aligned(16)));
  __shared__ float sc[32 * 33];
  const int tid = threadIdx.x;
  const size_t base = (size_t)blockIdx.x * 12288;   // 32*384
#pragma unroll
  for (int i = 0; i < 6; i++) {
    int cc = tid + i * 256;
    int row = cc / 48, c = cc % 48;
    *(ushortx8*)(cs + row * 392 + c * 8) = *(const ushortx8*)(cur16 + base + (size_t)cc * 8);
  }
  __syncthreads();
#pragma unroll
  for (int i = 0; i < 4; i++) {
    int p = tid + i * 256;
    int a = p >> 5, b = p & 31;
    const float* qrow = q32 + base + (size_t)a * 384;
    float s = 0.f;
    for (int kc = 0; kc < 48; kc++) {
      const float4* qp = (const float4*)(qrow + kc * 8);
      float4 qa = qp[0], qb = qp[1];
      ushortx8 cv = *(const ushortx8*)(cs + b * 392 + kc * 8);
      s += qa.x * bf2f(cv[0]) + qa.y * bf2f(cv[1]) + qa.z * bf2f(cv[2]) + qa.w * bf2f(cv[3])
         + qb.x * bf2f(cv[4]) + qb.y * bf2f(cv[5]) + qb.z * bf2f(cv[6]) + qb.w * bf2f(cv[7]);
    }
    sc[a * 33 + b] = s;
  }
  __syncthreads();
  if (tid < 32) {
    float mx = -1e30f;
    for (int b = 0; b < 32; b++) mx = fmaxf(mx, sc[tid * 33 + b]);
    float sum = 0.f; float ex[32];
    for (int b = 0; b < 32; b++) { float e = __expf(sc[tid * 33 + b] - mx); ex[b] = e; sum += e; }
    float inv = 1.f / sum;
    for (int b = 0; b < 32; b++) sc[tid * 33 + b] = ex[b] * inv;
  }
  __syncthreads();
#pragma unroll
  for (int i = 0; i < 6; i++) {
    int cc = tid + i * 256;
    int a = cc / 48, hc = cc % 48;
    float acc8[8] = {};
    for (int b = 0; b < 32; b++) {
      float wgt = sc[a * 33 + b];
      ushortx8 cv = *(const ushortx8*)(cs + b * 392 + hc * 8);
#pragma unroll
      for (int e = 0; e < 8; e++) acc8[e] += wgt * bf2f(cv[e]);
    }
    ushortx8 o;
#pragma unroll
    for (int e = 0; e < 8; e++) o[e] = f2bf(acc8[e]);
    *(ushortx8*)(z16 + base + (size_t)cc * 8) = o;
  }
}

// out[m][h] = sum_a (cur[m*32+a][h] + r[m*32+a][h])   fp32 out
__global__ void k_final(const ushort_t* __restrict__ cur16, const ushort_t* __restrict__ r16,
                        float* __restrict__ out) {
  int cid = blockIdx.x * 256 + threadIdx.x;
  if (cid >= 1024 * 48) return;
  int m = cid / 48, hc = cid % 48;
  float acc8[8] = {};
  size_t rb = (size_t)m * 12288 + hc * 8;
  for (int a = 0; a < 32; a++) {
    ushortx8 cu = *(const ushortx8*)(cur16 + rb + (size_t)a * 384);
    ushortx8 rr = *(const ushortx8*)(r16 + rb + (size_t)a * 384);
#pragma unroll
    for (int e = 0; e < 8; e++) acc8[e] += bf2f(cu[e]) + bf2f(rr[e]);
  }
  float* o = out + (size_t)m * 384 + hc * 8;
#pragma unroll
  for (int e = 0; e < 8; e++) o[e] = acc8[e];
}

// ---------------------------------------------------------------------------
extern "C" void kernel_launch(void* const* d_in, const int* in_sizes, int n_in,
                              void* d_out, int out_size, void* d_ws, size_t ws_size,
                              hipStream_t stream) {
  (void)in_sizes; (void)n_in; (void)out_size;
  const float* f_atoms = (const float*)d_in[0];
  const float* f_bonds = (const float*)d_in[1];
  const float* W_i = (const float*)d_in[2];
  const float* W_h = (const float*)d_in[3];
  const float* W_o = (const float*)d_in[4];
  const float* b_o = (const float*)d_in[5];
  const float* W_a = (const float*)d_in[6];
  const float* W_b = (const float*)d_in[7];
  const float* b_b = (const float*)d_in[8];
  const int* a2b = (const int*)d_in[9];
  const int* b2a = (const int*)d_in[10];
  const int* b2revb = (const int*)d_in[11];
  float* out = (float*)d_out;

  char* ws = (char*)d_ws;
  size_t off = 0;
  auto alloc = [&](size_t bytes) -> char* {
    char* p = ws + off; off += (bytes + 255) & ~(size_t)255; return p;
  };
  ushort_t* msg  = (ushort_t*)alloc(131073ull * 384 * 2);   // 100.66 MB
  ushort_t* fb16 = (ushort_t*)alloc(131073ull * 160 * 2);   //  41.94 MB
  char*     S    = alloc(60818688);                          //  60.82 MB (shared)
  ushort_t* wti  = (ushort_t*)alloc(384ull * 160 * 2);
  ushort_t* wthx = (ushort_t*)alloc(3ull * 384 * 544 * 2);
  ushort_t* wta  = (ushort_t*)alloc(384ull * 384 * 2);
  ushort_t* wtb  = (ushort_t*)alloc(384ull * 384 * 2);
  ushort_t* wto  = (ushort_t*)alloc(384ull * 544 * 2);
  if (ws_size < off) return;   // diagnostic guard (205.8 MB < proven 231 MB)

  // S region: amsg32 during depth loop; cath+cur16 afterwards.
  float*    amsg32 = (float*)S;                        // 32769*384*4 = 50.33 MB
  ushort_t* cath   = (ushort_t*)S;                     // 32769*544*2 = 35.65 MB
  ushort_t* cur16  = (ushort_t*)(S + 35652864);        // 32768*384*2 = 25.17 MB
  // msg region aliases (msg dead after k_amsg_cat):
  float*    q32 = (float*)msg;                         // 50.33 MB
  ushort_t* z16 = (ushort_t*)((char*)msg + 50331648);  // 25.17 MB
  ushort_t* r16 = (ushort_t*)((char*)msg + 75497472);  // 25.17 MB

  k_conv_fb<<<10241, 256, 0, stream>>>(f_bonds, fb16);
  k_conv_wt<<<582, 256, 0, stream>>>(W_i, W_h, W_a, W_b, W_o, wti, wthx, wta, wtb, wto);

  // bond init: msg = relu(f_bonds @ W_i)
  k_gemm<<<1024, 512, 0, stream>>>(nullptr, 0, 0, fb16 + 160, 160, 160,
                                   wti, 160, msg + 384, nullptr, nullptr, 1);

  for (int d = 0; d < 3; d++) {
    k_amsg32<<<6144, 256, 0, stream>>>(msg, a2b, amsg32);
    k_buildt<<<12288, 256, 0, stream>>>(amsg32, msg, b2a, b2revb);
    // msg = relu([t | fb] @ [W_h_d; W_i]) -- K=544, in-place per 128-stripe
    k_gemm<<<1024, 512, 0, stream>>>(msg + 384, 384, 384, fb16 + 160, 160, 160,
                                     wthx + (size_t)d * 208896, 544,
                                     msg + 384, nullptr, nullptr, 1);
  }
  // final a_msg -> cath cols 144..527 (bf16, one rounding), then atom features
  k_amsg_cat<<<6144, 256, 0, stream>>>(msg, a2b, cath);
  k_conv_fa<<<2560, 256, 0, stream>>>(f_atoms, cath);
  // cur = relu(cath @ W_o + b_o), atoms 1..32768
  k_gemm<<<256, 512, 0, stream>>>(cath + 544, 544, 544, nullptr, 0, 0,
                                  wto, 544, cur16, nullptr, b_o, 1);
  // q = cur @ W_a  (fp32 out; msg region is dead now)
  k_gemm<<<256, 512, 0, stream>>>(cur16, 384, 384, nullptr, 0, 0,
                                  wta, 384, nullptr, q32, nullptr, 0);
  k_attn<<<1024, 256, 0, stream>>>(q32, cur16, z16);
  // r = relu(z @ W_b + b_b)
  k_gemm<<<256, 512, 0, stream>>>(z16, 384, 384, nullptr, 0, 0,
                                  wtb, 384, r16, nullptr, b_b, 1);
  k_final<<<192, 256, 0, stream>>>(cur16, r16, out);
}

// Round 5
// 958.647 us; speedup vs baseline: 1.0796x; 1.0796x over previous
//
#include <hip/hip_runtime.h>
#include <cstdint>
#include <cstddef>

// ---------------------------------------------------------------------------
// QSAR D-MPNN, bf16 MFMA pipeline (round 5).
// Round-5 vs round-4 (replays diverged = race in asm vmcnt(7) barrier pipe):
//  * DROP raw-asm barriers (unsound for global_load_lds partial waits).
//    Single-buffer LDS + __syncthreads(), deterministic by construction.
//  * KEEP 256-thr / 64x384 tile (2 blocks/CU -> cross-block MFMA/drain
//    overlap, m114) and the XOR bank-conflict swizzle (validated, absmax 30).
//  * K-loop order: sync; read frags; sync; issue stage(k+1); MFMA(k) --
//    next-slab loads issue before MFMAs, drain deferred to next iter's sync.
// ---------------------------------------------------------------------------

typedef float  floatx4  __attribute__((ext_vector_type(4)));
typedef short  bf16x8   __attribute__((ext_vector_type(8)));
typedef unsigned short ushort_t;
typedef unsigned short ushortx8 __attribute__((ext_vector_type(8)));

#define DEV __device__ __forceinline__

DEV float bf2f(ushort_t u) {
  union { unsigned int i; float f; } v; v.i = ((unsigned int)u) << 16; return v.f;
}
DEV ushort_t f2bf(float f) {
  union { float f; unsigned int i; } v; v.f = f;
  unsigned int r = v.i + 0x7FFFu + ((v.i >> 16) & 1u);   // RNE
  return (ushort_t)(r >> 16);
}

#define GLD16(gp, lp)                                                          \
  __builtin_amdgcn_global_load_lds(                                            \
      (const __attribute__((address_space(1))) void*)(gp),                     \
      (__attribute__((address_space(3))) void*)(lp), 16, 0, 0)

// ---------------------------------------------------------------------------
// f_bonds fp32 [131073][150] -> fb16 [131073][160] (k-pad zeros)
__global__ void k_conv_fb(const float* __restrict__ fb, ushort_t* __restrict__ dst) {
  int cid = blockIdx.x * 256 + threadIdx.x;
  if (cid >= 131073 * 20) return;
  int row = cid / 20, j = cid % 20;
  const float* s = fb + (size_t)row * 150;
  ushortx8 o;
#pragma unroll
  for (int e = 0; e < 8; e++) { int col = j * 8 + e; o[e] = (col < 150) ? f2bf(s[col]) : (ushort_t)0; }
  *(ushortx8*)(dst + (size_t)row * 160 + j * 8) = o;
}

// f_atoms fp32 [32769][139] -> cath [32769][544] cols 0..143 + 528..543
__global__ void k_conv_fa(const float* __restrict__ fa, ushort_t* __restrict__ cath) {
  int cid = blockIdx.x * 256 + threadIdx.x;
  if (cid >= 32768 * 20) return;
  int a = cid / 20 + 1, j = cid % 20;
  int chunk = (j < 18) ? j : (48 + j);
  const float* s = fa + (size_t)a * 139;
  ushortx8 o;
#pragma unroll
  for (int e = 0; e < 8; e++) { int col = chunk * 8 + e; o[e] = (col < 139) ? f2bf(s[col]) : (ushort_t)0; }
  *(ushortx8*)(cath + (size_t)a * 544 + chunk * 8) = o;
}

// Weights -> bf16 transposed [N][Kpad].
__global__ void k_conv_wt(const float* __restrict__ Wi, const float* __restrict__ Wh,
                          const float* __restrict__ Wa, const float* __restrict__ Wb,
                          const float* __restrict__ Wo,
                          ushort_t* __restrict__ wti, ushort_t* __restrict__ wthx,
                          ushort_t* __restrict__ wta, ushort_t* __restrict__ wtb,
                          ushort_t* __restrict__ wto) {
  int cid = blockIdx.x * 256 + threadIdx.x;
  if (cid < 7680) {                       // wti [384][160]
    int n = cid / 20, kc = cid % 20; ushortx8 o;
#pragma unroll
    for (int e = 0; e < 8; e++) { int k = kc * 8 + e; o[e] = (k < 150) ? f2bf(Wi[(size_t)k * 384 + n]) : (ushort_t)0; }
    *(ushortx8*)(wti + (size_t)n * 160 + kc * 8) = o; return;
  }
  cid -= 7680;
  if (cid < 78336) {                      // wthx [3][384][544]: [W_h^T | W_i^T pad]
    int np = cid / 68, kc = cid % 68;
    int d = np / 384, n = np % 384; ushortx8 o;
#pragma unroll
    for (int e = 0; e < 8; e++) {
      float v;
      if (kc < 48) { int k = kc * 8 + e; v = Wh[(size_t)d * 147456 + (size_t)k * 384 + n]; }
      else { int k2 = (kc - 48) * 8 + e; v = (k2 < 150) ? Wi[(size_t)k2 * 384 + n] : 0.f; }
      o[e] = f2bf(v);
    }
    *(ushortx8*)(wthx + (size_t)np * 544 + kc * 8) = o; return;
  }
  cid -= 78336;
  if (cid < 18432) {                      // wta [384][384]
    int n = cid / 48, kc = cid % 48; ushortx8 o;
#pragma unroll
    for (int e = 0; e < 8; e++) { int k = kc * 8 + e; o[e] = f2bf(Wa[(size_t)k * 384 + n]); }
    *(ushortx8*)(wta + (size_t)n * 384 + kc * 8) = o; return;
  }
  cid -= 18432;
  if (cid < 18432) {                      // wtb
    int n = cid / 48, kc = cid % 48; ushortx8 o;
#pragma unroll
    for (int e = 0; e < 8; e++) { int k = kc * 8 + e; o[e] = f2bf(Wb[(size_t)k * 384 + n]); }
    *(ushortx8*)(wtb + (size_t)n * 384 + kc * 8) = o; return;
  }
  cid -= 18432;
  if (cid < 26112) {                      // wto [384][544] (cath col layout)
    int n = cid / 68, kc = cid % 68; ushortx8 o;
#pragma unroll
    for (int e = 0; e < 8; e++) {
      int k = kc * 8 + e; float v = 0.f;
      if (k < 139) v = Wo[(size_t)k * 384 + n];
      else if (k >= 144 && k < 528) v = Wo[(size_t)(k - 5) * 384 + n];
      o[e] = f2bf(v);
    }
    *(ushortx8*)(wto + (size_t)n * 544 + kc * 8) = o; return;
  }
}

// ---------------------------------------------------------------------------
// Stripe GEMM: one block = 64 output rows x full N=384, 256 threads = 4 waves,
// each 64x96 (4x6 16x16x32 MFMA tiles). Single 28 KB LDS buffer (448 rows x
// 32 cols bf16: rows 0..63 = A-tile, 64..447 = B-tile), __syncthreads()
// barriers. XOR swizzle on k-chunks so ds_read_b128 is ~conflict-free.
// A split: cols [0,K1) from A1 (lda1), [K1,K1+K2) from A2 (lda2).
// out = [relu](A @ Bt^T + bias) -> Cf (fp32) if non-null else Cb (bf16).
// In-place safe: a block reads only rows [m0,m0+64) (fully staged before
// epilogue) and writes exactly those rows across full N.
__global__ __launch_bounds__(256, 2) void k_gemm(
    const ushort_t* __restrict__ A1, int lda1, int K1,
    const ushort_t* __restrict__ A2, int lda2, int K2,
    const ushort_t* __restrict__ Bt, int ldb,
    ushort_t* __restrict__ Cb, float* __restrict__ Cf,
    const float* __restrict__ bias, int relu)
{
  __shared__ ushort_t LS[14336] __attribute__((aligned(16)));  // 28 KiB
  const int tid = threadIdx.x;
  const int w = tid >> 6, l = tid & 63;
  const int m0 = blockIdx.x << 6;
  const int lr = l & 15, quad = l >> 4;
  const int K1c = K1, K2c = K2;
  const int NI = (K1c + K2c) >> 5;

  floatx4 acc[4][6] = {};

  const int srow = l >> 2;                             // 0..15 in 16-row group
  const int kswz = ((l & 3) ^ (srow & 3)) << 3;        // swizzled k-offset
  const int rswz = (quad ^ (lr & 3)) << 3;             // read-side un-swizzle

  auto stage = [&](int k0) {
#pragma unroll
    for (int g = 0; g < 7; g++) {
      const int gi = w * 7 + g;                        // 16-row group 0..27
      const int cr = (gi << 4) + srow;                 // combined row 0..447
      ushort_t* lp = LS + ((size_t)gi << 9);           // wave-uniform base
      if (cr < 64) {                                   // A rows (uniform per gi)
        if (k0 < K1c) GLD16(A1 + (size_t)(m0 + cr) * lda1 + k0 + kswz, lp);
        else          GLD16(A2 + (size_t)(m0 + cr) * lda2 + (k0 - K1c) + kswz, lp);
      } else {                                         // B rows 0..383
        GLD16(Bt + (size_t)(cr - 64) * ldb + k0 + kswz, lp);
      }
    }
  };

  stage(0);
  for (int i = 0; i < NI; i++) {
    __syncthreads();                                   // slab i landed in LDS
    bf16x8 af[4], bfr[6];
#pragma unroll
    for (int mt = 0; mt < 4; mt++) {
      int R = (mt << 4) + lr;                          // A rows 0..63
      af[mt] = *(const bf16x8*)(LS + R * 32 + rswz);
    }
#pragma unroll
    for (int nt = 0; nt < 6; nt++) {
      int R = 64 + w * 96 + (nt << 4) + lr;            // this wave's B rows
      bfr[nt] = *(const bf16x8*)(LS + R * 32 + rswz);
    }
    __syncthreads();                                   // all frag reads done
    if (i + 1 < NI) stage((i + 1) << 5);               // overlaps MFMAs below
#pragma unroll
    for (int mt = 0; mt < 4; mt++)
#pragma unroll
      for (int nt = 0; nt < 6; nt++)
        acc[mt][nt] = __builtin_amdgcn_mfma_f32_16x16x32_bf16(af[mt], bfr[nt], acc[mt][nt], 0, 0, 0);
  }

#pragma unroll
  for (int mt = 0; mt < 4; mt++) {
#pragma unroll
    for (int nt = 0; nt < 6; nt++) {
      int colg = w * 96 + (nt << 4) + lr;
      float bv = bias ? bias[colg] : 0.f;
#pragma unroll
      for (int r = 0; r < 4; r++) {
        int rowg = m0 + (mt << 4) + (quad << 2) + r;
        size_t off = (size_t)rowg * 384 + colg;
        float v = acc[mt][nt][r] + bv;
        if (relu) v = fmaxf(v, 0.f);
        if (Cf) Cf[off] = v;
        else    Cb[off] = f2bf(v);
      }
    }
  }
}

// ---------------------------------------------------------------------------
// amsg32[a] = sum_{k<4} msg[a2b[a][k]]  in fp32 (atoms 1..32768)
__global__ void k_amsg32(const ushort_t* __restrict__ msg, const int* __restrict__ a2b,
                         float* __restrict__ amsg) {
  int cid = blockIdx.x * 256 + threadIdx.x;
  if (cid >= 32768 * 48) return;
  int a = (cid / 48) + 1, c = cid % 48;
  const int4 nb = *(const int4*)(a2b + (size_t)a * 4);
  ushortx8 x0 = *(const ushortx8*)(msg + (size_t)nb.x * 384 + c * 8);
  ushortx8 x1 = *(const ushortx8*)(msg + (size_t)nb.y * 384 + c * 8);
  ushortx8 x2 = *(const ushortx8*)(msg + (size_t)nb.z * 384 + c * 8);
  ushortx8 x3 = *(const ushortx8*)(msg + (size_t)nb.w * 384 + c * 8);
  float4 lo, hi;
  lo.x = bf2f(x0[0]) + bf2f(x1[0]) + bf2f(x2[0]) + bf2f(x3[0]);
  lo.y = bf2f(x0[1]) + bf2f(x1[1]) + bf2f(x2[1]) + bf2f(x3[1]);
  lo.z = bf2f(x0[2]) + bf2f(x1[2]) + bf2f(x2[2]) + bf2f(x3[2]);
  lo.w = bf2f(x0[3]) + bf2f(x1[3]) + bf2f(x2[3]) + bf2f(x3[3]);
  hi.x = bf2f(x0[4]) + bf2f(x1[4]) + bf2f(x2[4]) + bf2f(x3[4]);
  hi.y = bf2f(x0[5]) + bf2f(x1[5]) + bf2f(x2[5]) + bf2f(x3[5]);
  hi.z = bf2f(x0[6]) + bf2f(x1[6]) + bf2f(x2[6]) + bf2f(x3[6]);
  hi.w = bf2f(x0[7]) + bf2f(x1[7]) + bf2f(x2[7]) + bf2f(x3[7]);
  float4* d = (float4*)(amsg + (size_t)a * 384 + c * 8);
  d[0] = lo; d[1] = hi;
}

// a_msg (bf16) for the readout concat: cath[a][144..527]
__global__ void k_amsg_cat(const ushort_t* __restrict__ msg, const int* __restrict__ a2b,
                           ushort_t* __restrict__ cath) {
  int cid = blockIdx.x * 256 + threadIdx.x;
  if (cid >= 32768 * 48) return;
  int a = (cid / 48) + 1, c = cid % 48;
  const int4 nb = *(const int4*)(a2b + (size_t)a * 4);
  ushortx8 x0 = *(const ushortx8*)(msg + (size_t)nb.x * 384 + c * 8);
  ushortx8 x1 = *(const ushortx8*)(msg + (size_t)nb.y * 384 + c * 8);
  ushortx8 x2 = *(const ushortx8*)(msg + (size_t)nb.z * 384 + c * 8);
  ushortx8 x3 = *(const ushortx8*)(msg + (size_t)nb.w * 384 + c * 8);
  ushortx8 o;
#pragma unroll
  for (int e = 0; e < 8; e++)
    o[e] = f2bf(bf2f(x0[e]) + bf2f(x1[e]) + bf2f(x2[e]) + bf2f(x3[e]));
  *(ushortx8*)(cath + (size_t)a * 544 + 144 + c * 8) = o;
}

// In-place build_t over rev-bond pairs (b0=2p+1, b1=b2revb[b0]=b0+1):
//   t[b] = amsg32[b2a[b]] - msg[rev(b)], rounded once to bf16.
__global__ void k_buildt(const float* __restrict__ amsg, ushort_t* __restrict__ msg,
                         const int* __restrict__ b2a, const int* __restrict__ b2revb) {
  int cid = blockIdx.x * 256 + threadIdx.x;
  if (cid >= 65536 * 48) return;
  int p = cid / 48, c = cid % 48;
  int b0 = 2 * p + 1;
  int b1 = b2revb[b0];
  int a0 = b2a[b0], a1 = b2a[b1];
  ushortx8 m0v = *(const ushortx8*)(msg + (size_t)b0 * 384 + c * 8);
  ushortx8 m1v = *(const ushortx8*)(msg + (size_t)b1 * 384 + c * 8);
  const float4* s0p = (const float4*)(amsg + (size_t)a0 * 384 + c * 8);
  const float4* s1p = (const float4*)(amsg + (size_t)a1 * 384 + c * 8);
  float4 s0a = s0p[0], s0b = s0p[1];
  float4 s1a = s1p[0], s1b = s1p[1];
  ushortx8 o0, o1;
  o0[0] = f2bf(s0a.x - bf2f(m1v[0])); o0[1] = f2bf(s0a.y - bf2f(m1v[1]));
  o0[2] = f2bf(s0a.z - bf2f(m1v[2])); o0[3] = f2bf(s0a.w - bf2f(m1v[3]));
  o0[4] = f2bf(s0b.x - bf2f(m1v[4])); o0[5] = f2bf(s0b.y - bf2f(m1v[5]));
  o0[6] = f2bf(s0b.z - bf2f(m1v[6])); o0[7] = f2bf(s0b.w - bf2f(m1v[7]));
  o1[0] = f2bf(s1a.x - bf2f(m0v[0])); o1[1] = f2bf(s1a.y - bf2f(m0v[1]));
  o1[2] = f2bf(s1a.z - bf2f(m0v[2])); o1[3] = f2bf(s1a.w - bf2f(m0v[3]));
  o1[4] = f2bf(s1b.x - bf2f(m0v[4])); o1[5] = f2bf(s1b.y - bf2f(m0v[5]));
  o1[6] = f2bf(s1b.z - bf2f(m0v[6])); o1[7] = f2bf(s1b.w - bf2f(m0v[7]));
  *(ushortx8*)(msg + (size_t)b0 * 384 + c * 8) = o0;
  *(ushortx8*)(msg + (size_t)b1 * 384 + c * 8) = o1;
}

// ---------------------------------------------------------------------------
// Per-molecule attention: scores = q32@cur^T (fp32 q), row softmax, z=att@cur.
__global__ __launch_bounds__(256) void k_attn(const float* __restrict__ q32,
                                              const ushort_t* __restrict__ cur16,
                                              ushort_t* __restrict__ z16) {
  __shared__ ushort_t cs[32 * 392] __attribute__((aligned(16)));
  __shared__ float sc[32 * 33];
  const int tid = threadIdx.x;
  const size_t base = (size_t)blockIdx.x * 12288;
#pragma unroll
  for (int i = 0; i < 6; i++) {
    int cc = tid + i * 256;
    int row = cc / 48, c = cc % 48;
    *(ushortx8*)(cs + row * 392 + c * 8) = *(const ushortx8*)(cur16 + base + (size_t)cc * 8);
  }
  __syncthreads();
#pragma unroll
  for (int i = 0; i < 4; i++) {
    int p = tid + i * 256;
    int a = p >> 5, b = p & 31;
    const float* qrow = q32 + base + (size_t)a * 384;
    float s = 0.f;
    for (int kc = 0; kc < 48; kc++) {
      const float4* qp = (const float4*)(qrow + kc * 8);
      float4 qa = qp[0], qb = qp[1];
      ushortx8 cv = *(const ushortx8*)(cs + b * 392 + kc * 8);
      s += qa.x * bf2f(cv[0]) + qa.y * bf2f(cv[1]) + qa.z * bf2f(cv[2]) + qa.w * bf2f(cv[3])
         + qb.x * bf2f(cv[4]) + qb.y * bf2f(cv[5]) + qb.z * bf2f(cv[6]) + qb.w * bf2f(cv[7]);
    }
    sc[a * 33 + b] = s;
  }
  __syncthreads();
  if (tid < 32) {
    float mx = -1e30f;
    for (int b = 0; b < 32; b++) mx = fmaxf(mx, sc[tid * 33 + b]);
    float sum = 0.f; float ex[32];
    for (int b = 0; b < 32; b++) { float e = __expf(sc[tid * 33 + b] - mx); ex[b] = e; sum += e; }
    float inv = 1.f / sum;
    for (int b = 0; b < 32; b++) sc[tid * 33 + b] = ex[b] * inv;
  }
  __syncthreads();
#pragma unroll
  for (int i = 0; i < 6; i++) {
    int cc = tid + i * 256;
    int a = cc / 48, hc = cc % 48;
    float acc8[8] = {};
    for (int b = 0; b < 32; b++) {
      float wgt = sc[a * 33 + b];
      ushortx8 cv = *(const ushortx8*)(cs + b * 392 + hc * 8);
#pragma unroll
      for (int e = 0; e < 8; e++) acc8[e] += wgt * bf2f(cv[e]);
    }
    ushortx8 o;
#pragma unroll
    for (int e = 0; e < 8; e++) o[e] = f2bf(acc8[e]);
    *(ushortx8*)(z16 + base + (size_t)cc * 8) = o;
  }
}

// out[m][h] = sum_a (cur[m*32+a][h] + r[m*32+a][h])   fp32 out
__global__ void k_final(const ushort_t* __restrict__ cur16, const ushort_t* __restrict__ r16,
                        float* __restrict__ out) {
  int cid = blockIdx.x * 256 + threadIdx.x;
  if (cid >= 1024 * 48) return;
  int m = cid / 48, hc = cid % 48;
  float acc8[8] = {};
  size_t rb = (size_t)m * 12288 + hc * 8;
  for (int a = 0; a < 32; a++) {
    ushortx8 cu = *(const ushortx8*)(cur16 + rb + (size_t)a * 384);
    ushortx8 rr = *(const ushortx8*)(r16 + rb + (size_t)a * 384);
#pragma unroll
    for (int e = 0; e < 8; e++) acc8[e] += bf2f(cu[e]) + bf2f(rr[e]);
  }
  float* o = out + (size_t)m * 384 + hc * 8;
#pragma unroll
  for (int e = 0; e < 8; e++) o[e] = acc8[e];
}

// ---------------------------------------------------------------------------
extern "C" void kernel_launch(void* const* d_in, const int* in_sizes, int n_in,
                              void* d_out, int out_size, void* d_ws, size_t ws_size,
                              hipStream_t stream) {
  (void)in_sizes; (void)n_in; (void)out_size;
  const float* f_atoms = (const float*)d_in[0];
  const float* f_bonds = (const float*)d_in[1];
  const float* W_i = (const float*)d_in[2];
  const float* W_h = (const float*)d_in[3];
  const float* W_o = (const float*)d_in[4];
  const float* b_o = (const float*)d_in[5];
  const float* W_a = (const float*)d_in[6];
  const float* W_b = (const float*)d_in[7];
  const float* b_b = (const float*)d_in[8];
  const int* a2b = (const int*)d_in[9];
  const int* b2a = (const int*)d_in[10];
  const int* b2revb = (const int*)d_in[11];
  float* out = (float*)d_out;

  char* ws = (char*)d_ws;
  size_t off = 0;
  auto alloc = [&](size_t bytes) -> char* {
    char* p = ws + off; off += (bytes + 255) & ~(size_t)255; return p;
  };
  ushort_t* msg  = (ushort_t*)alloc(131073ull * 384 * 2);   // 100.66 MB
  ushort_t* fb16 = (ushort_t*)alloc(131073ull * 160 * 2);   //  41.94 MB
  char*     S    = alloc(60818688);                          //  60.82 MB (shared)
  ushort_t* wti  = (ushort_t*)alloc(384ull * 160 * 2);
  ushort_t* wthx = (ushort_t*)alloc(3ull * 384 * 544 * 2);
  ushort_t* wta  = (ushort_t*)alloc(384ull * 384 * 2);
  ushort_t* wtb  = (ushort_t*)alloc(384ull * 384 * 2);
  ushort_t* wto  = (ushort_t*)alloc(384ull * 544 * 2);
  if (ws_size < off) return;   // guard (205.8 MB < proven 231 MB)

  // S region: amsg32 during depth loop; cath+cur16 afterwards.
  float*    amsg32 = (float*)S;
  ushort_t* cath   = (ushort_t*)S;
  ushort_t* cur16  = (ushort_t*)(S + 35652864);
  // msg region aliases (msg dead after k_amsg_cat):
  float*    q32 = (float*)msg;
  ushort_t* z16 = (ushort_t*)((char*)msg + 50331648);
  ushort_t* r16 = (ushort_t*)((char*)msg + 75497472);

  k_conv_fb<<<10241, 256, 0, stream>>>(f_bonds, fb16);
  k_conv_wt<<<582, 256, 0, stream>>>(W_i, W_h, W_a, W_b, W_o, wti, wthx, wta, wtb, wto);

  // bond init: msg = relu(f_bonds @ W_i)
  k_gemm<<<2048, 256, 0, stream>>>(nullptr, 0, 0, fb16 + 160, 160, 160,
                                   wti, 160, msg + 384, nullptr, nullptr, 1);

  for (int d = 0; d < 3; d++) {
    k_amsg32<<<6144, 256, 0, stream>>>(msg, a2b, amsg32);
    k_buildt<<<12288, 256, 0, stream>>>(amsg32, msg, b2a, b2revb);
    // msg = relu([t | fb] @ [W_h_d; W_i]) -- K=544, in-place per 64-stripe
    k_gemm<<<2048, 256, 0, stream>>>(msg + 384, 384, 384, fb16 + 160, 160, 160,
                                     wthx + (size_t)d * 208896, 544,
                                     msg + 384, nullptr, nullptr, 1);
  }
  // final a_msg -> cath cols 144..527, then atom features
  k_amsg_cat<<<6144, 256, 0, stream>>>(msg, a2b, cath);
  k_conv_fa<<<2560, 256, 0, stream>>>(f_atoms, cath);
  // cur = relu(cath @ W_o + b_o)
  k_gemm<<<512, 256, 0, stream>>>(cath + 544, 544, 544, nullptr, 0, 0,
                                  wto, 544, cur16, nullptr, b_o, 1);
  // q = cur @ W_a  (fp32 out)
  k_gemm<<<512, 256, 0, stream>>>(cur16, 384, 384, nullptr, 0, 0,
                                  wta, 384, nullptr, q32, nullptr, 0);
  k_attn<<<1024, 256, 0, stream>>>(q32, cur16, z16);
  // r = relu(z @ W_b + b_b)
  k_gemm<<<512, 256, 0, stream>>>(z16, 384, 384, nullptr, 0, 0,
                                  wtb, 384, r16, nullptr, b_b, 1);
  k_final<<<192, 256, 0, stream>>>(cur16, r16, out);
}

// Round 6
// 882.754 us; speedup vs baseline: 1.1724x; 1.0860x over previous
//
#include <hip/hip_runtime.h>
#include <cstdint>
#include <cstddef>

// ---------------------------------------------------------------------------
// QSAR D-MPNN, bf16 MFMA pipeline (round 6).
// Round-6 vs round-5 (958 us, depth GEMMs 116 us, flat ~20% profile =
// per-slab fixed-cost bound):
//  * BK=64 K-slabs (K padded to 576/192): 17 -> 9 slabs per depth GEMM,
//    halving barrier+latency events. LDS 448 rows x 128 B = 56 KB, still
//    2 blocks/CU. Slab computed as two K=32 sub-steps; sub1's MFMA overlaps
//    stage(next); second barrier drains nothing.
//  * XOR swizzle by row&7 (row stride = exactly 32 banks -> naive reads
//    would serialize 16 lanes on a 4-bank group).
//  * Bank-conflict counter shown structural (identical 5.57M across
//    different swizzles, = 4x ds_read count) -> not a target anymore.
// ---------------------------------------------------------------------------

typedef float  floatx4  __attribute__((ext_vector_type(4)));
typedef short  bf16x8   __attribute__((ext_vector_type(8)));
typedef unsigned short ushort_t;
typedef unsigned short ushortx8 __attribute__((ext_vector_type(8)));

#define DEV __device__ __forceinline__

DEV float bf2f(ushort_t u) {
  union { unsigned int i; float f; } v; v.i = ((unsigned int)u) << 16; return v.f;
}
DEV ushort_t f2bf(float f) {
  union { float f; unsigned int i; } v; v.f = f;
  unsigned int r = v.i + 0x7FFFu + ((v.i >> 16) & 1u);   // RNE
  return (ushort_t)(r >> 16);
}

#define GLD16(gp, lp)                                                          \
  __builtin_amdgcn_global_load_lds(                                            \
      (const __attribute__((address_space(1))) void*)(gp),                     \
      (__attribute__((address_space(3))) void*)(lp), 16, 0, 0)

// ---------------------------------------------------------------------------
// f_bonds fp32 [131073][150] -> fb192 [131073][192] (k-pad zeros)
__global__ void k_conv_fb(const float* __restrict__ fb, ushort_t* __restrict__ dst) {
  int cid = blockIdx.x * 256 + threadIdx.x;
  if (cid >= 131073 * 24) return;
  int row = cid / 24, j = cid % 24;
  const float* s = fb + (size_t)row * 150;
  ushortx8 o;
#pragma unroll
  for (int e = 0; e < 8; e++) { int col = j * 8 + e; o[e] = (col < 150) ? f2bf(s[col]) : (ushort_t)0; }
  *(ushortx8*)(dst + (size_t)row * 192 + j * 8) = o;
}

// f_atoms fp32 [32769][139] -> cath [32769][576] cols 0..143 + 528..575
__global__ void k_conv_fa(const float* __restrict__ fa, ushort_t* __restrict__ cath) {
  int cid = blockIdx.x * 256 + threadIdx.x;
  if (cid >= 32768 * 24) return;
  int a = cid / 24 + 1, j = cid % 24;
  int chunk = (j < 18) ? j : (48 + j);          // 18..23 -> 66..71 (cols 528..575)
  const float* s = fa + (size_t)a * 139;
  ushortx8 o;
#pragma unroll
  for (int e = 0; e < 8; e++) { int col = chunk * 8 + e; o[e] = (col < 139) ? f2bf(s[col]) : (ushort_t)0; }
  *(ushortx8*)(cath + (size_t)a * 576 + chunk * 8) = o;
}

// Weights -> bf16 transposed [N][Kpad].
//  wti [384][192], wthx [3][384][576] = [W_h^T | W_i^T pad], wta/wtb [384][384],
//  wto [384][576] remapped to cath col layout.
__global__ void k_conv_wt(const float* __restrict__ Wi, const float* __restrict__ Wh,
                          const float* __restrict__ Wa, const float* __restrict__ Wb,
                          const float* __restrict__ Wo,
                          ushort_t* __restrict__ wti, ushort_t* __restrict__ wthx,
                          ushort_t* __restrict__ wta, ushort_t* __restrict__ wtb,
                          ushort_t* __restrict__ wto) {
  int cid = blockIdx.x * 256 + threadIdx.x;
  if (cid < 9216) {                       // wti [384][192]
    int n = cid / 24, kc = cid % 24; ushortx8 o;
#pragma unroll
    for (int e = 0; e < 8; e++) { int k = kc * 8 + e; o[e] = (k < 150) ? f2bf(Wi[(size_t)k * 384 + n]) : (ushort_t)0; }
    *(ushortx8*)(wti + (size_t)n * 192 + kc * 8) = o; return;
  }
  cid -= 9216;
  if (cid < 82944) {                      // wthx [3][384][576]
    int np = cid / 72, kc = cid % 72;
    int d = np / 384, n = np % 384; ushortx8 o;
#pragma unroll
    for (int e = 0; e < 8; e++) {
      float v = 0.f;
      if (kc < 48) { int k = kc * 8 + e; v = Wh[(size_t)d * 147456 + (size_t)k * 384 + n]; }
      else { int k2 = (kc - 48) * 8 + e; v = (k2 < 150) ? Wi[(size_t)k2 * 384 + n] : 0.f; }
      o[e] = f2bf(v);
    }
    *(ushortx8*)(wthx + (size_t)np * 576 + kc * 8) = o; return;
  }
  cid -= 82944;
  if (cid < 18432) {                      // wta [384][384]
    int n = cid / 48, kc = cid % 48; ushortx8 o;
#pragma unroll
    for (int e = 0; e < 8; e++) { int k = kc * 8 + e; o[e] = f2bf(Wa[(size_t)k * 384 + n]); }
    *(ushortx8*)(wta + (size_t)n * 384 + kc * 8) = o; return;
  }
  cid -= 18432;
  if (cid < 18432) {                      // wtb
    int n = cid / 48, kc = cid % 48; ushortx8 o;
#pragma unroll
    for (int e = 0; e < 8; e++) { int k = kc * 8 + e; o[e] = f2bf(Wb[(size_t)k * 384 + n]); }
    *(ushortx8*)(wtb + (size_t)n * 384 + kc * 8) = o; return;
  }
  cid -= 18432;
  if (cid < 27648) {                      // wto [384][576] (cath col layout)
    int n = cid / 72, kc = cid % 72; ushortx8 o;
#pragma unroll
    for (int e = 0; e < 8; e++) {
      int k = kc * 8 + e; float v = 0.f;
      if (k < 139) v = Wo[(size_t)k * 384 + n];
      else if (k >= 144 && k < 528) v = Wo[(size_t)(k - 5) * 384 + n];
      o[e] = f2bf(v);
    }
    *(ushortx8*)(wto + (size_t)n * 576 + kc * 8) = o; return;
  }
}

// ---------------------------------------------------------------------------
// Stripe GEMM v3 (BK=64): one block = 64 rows x N=384, 256 thr = 4 waves,
// each 64x96 (4x6 MFMA tiles, two K=32 sub-steps per slab).
// LDS: 448 rows x 64 elem (A rows 0..63, B rows 64..447) = 56 KB, 1 buffer.
// Staging: 56 subgroups of 8 rows; one GLD16 per subgroup (64 lanes x 16 B);
// lane l -> row l>>3, slot l&7, staged k-chunk (l&7)^(l>>3) [xor swizzle].
// Read slot for (row R, chunk j) = j ^ (R&7); R&7 == lr&7 for all frag rows.
// K multiple of 64; A cols [0,K1) from A1, [K1,K1+K2) from A2 (per-lane
// boundary check handles straddle). out = [relu](A@Bt^T + bias) -> Cf|Cb.
// In-place safe: block reads only rows [m0,m0+64), writes those rows.
__global__ __launch_bounds__(256, 2) void k_gemm(
    const ushort_t* __restrict__ A1, int lda1, int K1,
    const ushort_t* __restrict__ A2, int lda2, int K2,
    const ushort_t* __restrict__ Bt, int ldb,
    ushort_t* __restrict__ Cb, float* __restrict__ Cf,
    const float* __restrict__ bias, int relu)
{
  __shared__ ushort_t LS[448 * 64] __attribute__((aligned(16)));  // 56 KiB
  const int tid = threadIdx.x;
  const int w = tid >> 6, l = tid & 63;
  const int m0 = blockIdx.x << 6;
  const int lr = l & 15, quad = l >> 4;
  const int NI = (K1 + K2) >> 6;

  floatx4 acc[4][6] = {};

  const int srow8 = l >> 3;             // 0..7 within 8-row subgroup
  const int skc   = (l & 7) ^ srow8;    // staged k-chunk (xor swizzle)

  auto stage = [&](int k0) {
#pragma unroll
    for (int g = 0; g < 14; g++) {
      const int sg = w + (g << 2);             // subgroup 0..55
      const int r  = (sg << 3) + srow8;        // LDS row 0..447
      ushort_t* lp = LS + ((size_t)sg << 9);   // 1024 B per subgroup
      const int kk = k0 + (skc << 3);
      if (r < 64) {
        if (kk < K1) GLD16(A1 + (size_t)(m0 + r) * lda1 + kk, lp);
        else         GLD16(A2 + (size_t)(m0 + r) * lda2 + (kk - K1), lp);
      } else {
        GLD16(Bt + (size_t)(r - 64) * ldb + kk, lp);
      }
    }
  };

  const int rsw = (lr & 7);
  stage(0);
  for (int i = 0; i < NI; i++) {
    __syncthreads();                                   // slab i landed
    bf16x8 af0[4], bf0[6], af1[4], bf1[6];
#pragma unroll
    for (int mt = 0; mt < 4; mt++) {
      int R = (mt << 4) + lr;
      af0[mt] = *(const bf16x8*)(LS + (size_t)R * 64 + ((quad ^ rsw) << 3));
    }
#pragma unroll
    for (int nt = 0; nt < 6; nt++) {
      int R = 64 + w * 96 + (nt << 4) + lr;
      bf0[nt] = *(const bf16x8*)(LS + (size_t)R * 64 + ((quad ^ rsw) << 3));
    }
#pragma unroll
    for (int mt = 0; mt < 4; mt++)
#pragma unroll
      for (int nt = 0; nt < 6; nt++)
        acc[mt][nt] = __builtin_amdgcn_mfma_f32_16x16x32_bf16(af0[mt], bf0[nt], acc[mt][nt], 0, 0, 0);
#pragma unroll
    for (int mt = 0; mt < 4; mt++) {
      int R = (mt << 4) + lr;
      af1[mt] = *(const bf16x8*)(LS + (size_t)R * 64 + (((4 + quad) ^ rsw) << 3));
    }
#pragma unroll
    for (int nt = 0; nt < 6; nt++) {
      int R = 64 + w * 96 + (nt << 4) + lr;
      bf1[nt] = *(const bf16x8*)(LS + (size_t)R * 64 + (((4 + quad) ^ rsw) << 3));
    }
    __syncthreads();                                   // all reads done
    if (i + 1 < NI) stage((i + 1) << 6);               // overlaps sub1 MFMAs
#pragma unroll
    for (int mt = 0; mt < 4; mt++)
#pragma unroll
      for (int nt = 0; nt < 6; nt++)
        acc[mt][nt] = __builtin_amdgcn_mfma_f32_16x16x32_bf16(af1[mt], bf1[nt], acc[mt][nt], 0, 0, 0);
  }

#pragma unroll
  for (int mt = 0; mt < 4; mt++) {
#pragma unroll
    for (int nt = 0; nt < 6; nt++) {
      int colg = w * 96 + (nt << 4) + lr;
      float bv = bias ? bias[colg] : 0.f;
#pragma unroll
      for (int r = 0; r < 4; r++) {
        int rowg = m0 + (mt << 4) + (quad << 2) + r;
        size_t off = (size_t)rowg * 384 + colg;
        float v = acc[mt][nt][r] + bv;
        if (relu) v = fmaxf(v, 0.f);
        if (Cf) Cf[off] = v;
        else    Cb[off] = f2bf(v);
      }
    }
  }
}

// ---------------------------------------------------------------------------
// amsg32[a] = sum_{k<4} msg[a2b[a][k]]  in fp32 (atoms 1..32768)
__global__ void k_amsg32(const ushort_t* __restrict__ msg, const int* __restrict__ a2b,
                         float* __restrict__ amsg) {
  int cid = blockIdx.x * 256 + threadIdx.x;
  if (cid >= 32768 * 48) return;
  int a = (cid / 48) + 1, c = cid % 48;
  const int4 nb = *(const int4*)(a2b + (size_t)a * 4);
  ushortx8 x0 = *(const ushortx8*)(msg + (size_t)nb.x * 384 + c * 8);
  ushortx8 x1 = *(const ushortx8*)(msg + (size_t)nb.y * 384 + c * 8);
  ushortx8 x2 = *(const ushortx8*)(msg + (size_t)nb.z * 384 + c * 8);
  ushortx8 x3 = *(const ushortx8*)(msg + (size_t)nb.w * 384 + c * 8);
  float4 lo, hi;
  lo.x = bf2f(x0[0]) + bf2f(x1[0]) + bf2f(x2[0]) + bf2f(x3[0]);
  lo.y = bf2f(x0[1]) + bf2f(x1[1]) + bf2f(x2[1]) + bf2f(x3[1]);
  lo.z = bf2f(x0[2]) + bf2f(x1[2]) + bf2f(x2[2]) + bf2f(x3[2]);
  lo.w = bf2f(x0[3]) + bf2f(x1[3]) + bf2f(x2[3]) + bf2f(x3[3]);
  hi.x = bf2f(x0[4]) + bf2f(x1[4]) + bf2f(x2[4]) + bf2f(x3[4]);
  hi.y = bf2f(x0[5]) + bf2f(x1[5]) + bf2f(x2[5]) + bf2f(x3[5]);
  hi.z = bf2f(x0[6]) + bf2f(x1[6]) + bf2f(x2[6]) + bf2f(x3[6]);
  hi.w = bf2f(x0[7]) + bf2f(x1[7]) + bf2f(x2[7]) + bf2f(x3[7]);
  float4* d = (float4*)(amsg + (size_t)a * 384 + c * 8);
  d[0] = lo; d[1] = hi;
}

// a_msg (bf16) for readout concat: cath[a][144..527]
__global__ void k_amsg_cat(const ushort_t* __restrict__ msg, const int* __restrict__ a2b,
                           ushort_t* __restrict__ cath) {
  int cid = blockIdx.x * 256 + threadIdx.x;
  if (cid >= 32768 * 48) return;
  int a = (cid / 48) + 1, c = cid % 48;
  const int4 nb = *(const int4*)(a2b + (size_t)a * 4);
  ushortx8 x0 = *(const ushortx8*)(msg + (size_t)nb.x * 384 + c * 8);
  ushortx8 x1 = *(const ushortx8*)(msg + (size_t)nb.y * 384 + c * 8);
  ushortx8 x2 = *(const ushortx8*)(msg + (size_t)nb.z * 384 + c * 8);
  ushortx8 x3 = *(const ushortx8*)(msg + (size_t)nb.w * 384 + c * 8);
  ushortx8 o;
#pragma unroll
  for (int e = 0; e < 8; e++)
    o[e] = f2bf(bf2f(x0[e]) + bf2f(x1[e]) + bf2f(x2[e]) + bf2f(x3[e]));
  *(ushortx8*)(cath + (size_t)a * 576 + 144 + c * 8) = o;
}

// In-place build_t over rev-bond pairs (b0=2p+1, b1=b2revb[b0]):
//   t[b] = amsg32[b2a[b]] - msg[rev(b)], rounded once to bf16.
__global__ void k_buildt(const float* __restrict__ amsg, ushort_t* __restrict__ msg,
                         const int* __restrict__ b2a, const int* __restrict__ b2revb) {
  int cid = blockIdx.x * 256 + threadIdx.x;
  if (cid >= 65536 * 48) return;
  int p = cid / 48, c = cid % 48;
  int b0 = 2 * p + 1;
  int b1 = b2revb[b0];
  int a0 = b2a[b0], a1 = b2a[b1];
  ushortx8 m0v = *(const ushortx8*)(msg + (size_t)b0 * 384 + c * 8);
  ushortx8 m1v = *(const ushortx8*)(msg + (size_t)b1 * 384 + c * 8);
  const float4* s0p = (const float4*)(amsg + (size_t)a0 * 384 + c * 8);
  const float4* s1p = (const float4*)(amsg + (size_t)a1 * 384 + c * 8);
  float4 s0a = s0p[0], s0b = s0p[1];
  float4 s1a = s1p[0], s1b = s1p[1];
  ushortx8 o0, o1;
  o0[0] = f2bf(s0a.x - bf2f(m1v[0])); o0[1] = f2bf(s0a.y - bf2f(m1v[1]));
  o0[2] = f2bf(s0a.z - bf2f(m1v[2])); o0[3] = f2bf(s0a.w - bf2f(m1v[3]));
  o0[4] = f2bf(s0b.x - bf2f(m1v[4])); o0[5] = f2bf(s0b.y - bf2f(m1v[5]));
  o0[6] = f2bf(s0b.z - bf2f(m1v[6])); o0[7] = f2bf(s0b.w - bf2f(m1v[7]));
  o1[0] = f2bf(s1a.x - bf2f(m0v[0])); o1[1] = f2bf(s1a.y - bf2f(m0v[1]));
  o1[2] = f2bf(s1a.z - bf2f(m0v[2])); o1[3] = f2bf(s1a.w - bf2f(m0v[3]));
  o1[4] = f2bf(s1b.x - bf2f(m0v[4])); o1[5] = f2bf(s1b.y - bf2f(m0v[5]));
  o1[6] = f2bf(s1b.z - bf2f(m0v[6])); o1[7] = f2bf(s1b.w - bf2f(m0v[7]));
  *(ushortx8*)(msg + (size_t)b0 * 384 + c * 8) = o0;
  *(ushortx8*)(msg + (size_t)b1 * 384 + c * 8) = o1;
}

// ---------------------------------------------------------------------------
// Per-molecule attention: scores = q32@cur^T (fp32 q), row softmax, z=att@cur.
__global__ __launch_bounds__(256) void k_attn(const float* __restrict__ q32,
                                              const ushort_t* __restrict__ cur16,
                                              ushort_t* __restrict__ z16) {
  __shared__ ushort_t cs[32 * 392] __attribute__((aligned(16)));
  __shared__ float sc[32 * 33];
  const int tid = threadIdx.x;
  const size_t base = (size_t)blockIdx.x * 12288;
#pragma unroll
  for (int i = 0; i < 6; i++) {
    int cc = tid + i * 256;
    int row = cc / 48, c = cc % 48;
    *(ushortx8*)(cs + row * 392 + c * 8) = *(const ushortx8*)(cur16 + base + (size_t)cc * 8);
  }
  __syncthreads();
#pragma unroll
  for (int i = 0; i < 4; i++) {
    int p = tid + i * 256;
    int a = p >> 5, b = p & 31;
    const float* qrow = q32 + base + (size_t)a * 384;
    float s = 0.f;
    for (int kc = 0; kc < 48; kc++) {
      const float4* qp = (const float4*)(qrow + kc * 8);
      float4 qa = qp[0], qb = qp[1];
      ushortx8 cv = *(const ushortx8*)(cs + b * 392 + kc * 8);
      s += qa.x * bf2f(cv[0]) + qa.y * bf2f(cv[1]) + qa.z * bf2f(cv[2]) + qa.w * bf2f(cv[3])
         + qb.x * bf2f(cv[4]) + qb.y * bf2f(cv[5]) + qb.z * bf2f(cv[6]) + qb.w * bf2f(cv[7]);
    }
    sc[a * 33 + b] = s;
  }
  __syncthreads();
  if (tid < 32) {
    float mx = -1e30f;
    for (int b = 0; b < 32; b++) mx = fmaxf(mx, sc[tid * 33 + b]);
    float sum = 0.f; float ex[32];
    for (int b = 0; b < 32; b++) { float e = __expf(sc[tid * 33 + b] - mx); ex[b] = e; sum += e; }
    float inv = 1.f / sum;
    for (int b = 0; b < 32; b++) sc[tid * 33 + b] = ex[b] * inv;
  }
  __syncthreads();
#pragma unroll
  for (int i = 0; i < 6; i++) {
    int cc = tid + i * 256;
    int a = cc / 48, hc = cc % 48;
    float acc8[8] = {};
    for (int b = 0; b < 32; b++) {
      float wgt = sc[a * 33 + b];
      ushortx8 cv = *(const ushortx8*)(cs + b * 392 + hc * 8);
#pragma unroll
      for (int e = 0; e < 8; e++) acc8[e] += wgt * bf2f(cv[e]);
    }
    ushortx8 o;
#pragma unroll
    for (int e = 0; e < 8; e++) o[e] = f2bf(acc8[e]);
    *(ushortx8*)(z16 + base + (size_t)cc * 8) = o;
  }
}

// out[m][h] = sum_a (cur[m*32+a][h] + r[m*32+a][h])   fp32 out
__global__ void k_final(const ushort_t* __restrict__ cur16, const ushort_t* __restrict__ r16,
                        float* __restrict__ out) {
  int cid = blockIdx.x * 256 + threadIdx.x;
  if (cid >= 1024 * 48) return;
  int m = cid / 48, hc = cid % 48;
  float acc8[8] = {};
  size_t rb = (size_t)m * 12288 + hc * 8;
  for (int a = 0; a < 32; a++) {
    ushortx8 cu = *(const ushortx8*)(cur16 + rb + (size_t)a * 384);
    ushortx8 rr = *(const ushortx8*)(r16 + rb + (size_t)a * 384);
#pragma unroll
    for (int e = 0; e < 8; e++) acc8[e] += bf2f(cu[e]) + bf2f(rr[e]);
  }
  float* o = out + (size_t)m * 384 + hc * 8;
#pragma unroll
  for (int e = 0; e < 8; e++) o[e] = acc8[e];
}

// ---------------------------------------------------------------------------
extern "C" void kernel_launch(void* const* d_in, const int* in_sizes, int n_in,
                              void* d_out, int out_size, void* d_ws, size_t ws_size,
                              hipStream_t stream) {
  (void)in_sizes; (void)n_in; (void)out_size;
  const float* f_atoms = (const float*)d_in[0];
  const float* f_bonds = (const float*)d_in[1];
  const float* W_i = (const float*)d_in[2];
  const float* W_h = (const float*)d_in[3];
  const float* W_o = (const float*)d_in[4];
  const float* b_o = (const float*)d_in[5];
  const float* W_a = (const float*)d_in[6];
  const float* W_b = (const float*)d_in[7];
  const float* b_b = (const float*)d_in[8];
  const int* a2b = (const int*)d_in[9];
  const int* b2a = (const int*)d_in[10];
  const int* b2revb = (const int*)d_in[11];
  float* out = (float*)d_out;

  char* ws = (char*)d_ws;
  size_t off = 0;
  auto alloc = [&](size_t bytes) -> char* {
    char* p = ws + off; off += (bytes + 255) & ~(size_t)255; return p;
  };
  ushort_t* msg   = (ushort_t*)alloc(131073ull * 384 * 2);   // 100.66 MB
  ushort_t* fb192 = (ushort_t*)alloc(131073ull * 192 * 2);   //  50.33 MB
  char*     S     = alloc(62915712);                          //  62.92 MB (shared)
  ushort_t* wti   = (ushort_t*)alloc(384ull * 192 * 2);
  ushort_t* wthx  = (ushort_t*)alloc(3ull * 384 * 576 * 2);
  ushort_t* wta   = (ushort_t*)alloc(384ull * 384 * 2);
  ushort_t* wtb   = (ushort_t*)alloc(384ull * 384 * 2);
  ushort_t* wto   = (ushort_t*)alloc(384ull * 576 * 2);
  if (ws_size < off) return;   // guard (~216.8 MB < proven 231 MB)

  // S region: amsg32 during depth loop; cath+cur16 afterwards.
  float*    amsg32 = (float*)S;                        // 50.33 MB
  ushort_t* cath   = (ushort_t*)S;                     // 32769*576*2 = 37.75 MB
  ushort_t* cur16  = (ushort_t*)(S + 37749888);        // 25.17 MB
  // msg region aliases (msg dead after k_amsg_cat):
  float*    q32 = (float*)msg;                         // 50.33 MB
  ushort_t* z16 = (ushort_t*)((char*)msg + 50331648);  // 25.17 MB
  ushort_t* r16 = (ushort_t*)((char*)msg + 75497472);  // 25.17 MB

  k_conv_fb<<<12289, 256, 0, stream>>>(f_bonds, fb192);
  k_conv_wt<<<612, 256, 0, stream>>>(W_i, W_h, W_a, W_b, W_o, wti, wthx, wta, wtb, wto);

  // bond init: msg = relu(f_bonds @ W_i)   K=192, 3 slabs
  k_gemm<<<2048, 256, 0, stream>>>(nullptr, 0, 0, fb192 + 192, 192, 192,
                                   wti, 192, msg + 384, nullptr, nullptr, 1);

  for (int d = 0; d < 3; d++) {
    k_amsg32<<<6144, 256, 0, stream>>>(msg, a2b, amsg32);
    k_buildt<<<12288, 256, 0, stream>>>(amsg32, msg, b2a, b2revb);
    // msg = relu([t | fb] @ [W_h_d; W_i]) -- K=576, 9 slabs, in-place
    k_gemm<<<2048, 256, 0, stream>>>(msg + 384, 384, 384, fb192 + 192, 192, 192,
                                     wthx + (size_t)d * 221184, 576,
                                     msg + 384, nullptr, nullptr, 1);
  }
  // final a_msg -> cath cols 144..527, then atom features
  k_amsg_cat<<<6144, 256, 0, stream>>>(msg, a2b, cath);
  k_conv_fa<<<3072, 256, 0, stream>>>(f_atoms, cath);
  // cur = relu(cath @ W_o + b_o)   K=576
  k_gemm<<<512, 256, 0, stream>>>(cath + 576, 576, 576, nullptr, 0, 0,
                                  wto, 576, cur16, nullptr, b_o, 1);
  // q = cur @ W_a  (fp32 out)   K=384
  k_gemm<<<512, 256, 0, stream>>>(cur16, 384, 384, nullptr, 0, 0,
                                  wta, 384, nullptr, q32, nullptr, 0);
  k_attn<<<1024, 256, 0, stream>>>(q32, cur16, z16);
  // r = relu(z @ W_b + b_b)   K=384
  k_gemm<<<512, 256, 0, stream>>>(z16, 384, 384, nullptr, 0, 0,
                                  wtb, 384, r16, nullptr, b_b, 1);
  k_final<<<192, 256, 0, stream>>>(cur16, r16, out);
}